// Round 21
// baseline (405.902 us; speedup 1.0000x reference)
//
#include <hip/hip_runtime.h>
#include <hip/hip_bf16.h>
#include <stdint.h>

#define T_TOK 4096
#define DM 1024
#define DF 4096
#define NE 8
#define SPLITK2 4
#define PGRID 256

using bf16x8 = __attribute__((ext_vector_type(8))) short;
using f32x4  = __attribute__((ext_vector_type(4))) float;
using u16x8  = __attribute__((ext_vector_type(8))) unsigned short;

#define MFMA16(a, b, c) __builtin_amdgcn_mfma_f32_16x16x32_bf16((a), (b), (c), 0, 0, 0)
#define VM5 asm volatile("s_waitcnt vmcnt(5)" ::: "memory")
#define VM0 asm volatile("s_waitcnt vmcnt(0)" ::: "memory")
#define BARX do { __builtin_amdgcn_s_barrier(); __builtin_amdgcn_sched_barrier(0); } while (0)
#define LGKM0 do { asm volatile("s_waitcnt lgkmcnt(0)" ::: "memory"); \
                   __builtin_amdgcn_sched_barrier(0); } while (0)

__device__ __forceinline__ unsigned short f2bf(float f) {
  union { float f; uint32_t u; } v; v.f = f;
  return (unsigned short)((v.u + 0x7FFFu + ((v.u >> 16) & 1u)) >> 16);
}

__device__ __forceinline__ void gload16(const void* g, void* l) {
  __builtin_amdgcn_global_load_lds((const __attribute__((address_space(1))) void*)g,
                                   (__attribute__((address_space(3))) void*)l, 16, 0, 0);
}

// ------- fused prep: router (blocks 0..1023, no atomics) + w1 transpose (1024..9215) -------
__global__ __launch_bounds__(256) void prep_kernel(
    const float* __restrict__ w1, unsigned short* __restrict__ w1t,
    const float* __restrict__ x, const float* __restrict__ noise,
    const float* __restrict__ rw, const float* __restrict__ rb,
    const float* __restrict__ nw, const float* __restrict__ nb,
    float* __restrict__ out_gate,
    int* __restrict__ tok_e, float* __restrict__ tok_g,
    unsigned short* __restrict__ xbf) {
  __shared__ float tile[64][65];
  int b = blockIdx.x;
  int t = threadIdx.x;
  if (b >= 1024) {
    int bb = b - 1024;
    int mat = bb >> 10, ty = bb & 1023;
    int R0 = (ty >> 6) * 64, C0 = (ty & 63) * 64;   // R=1024, C=4096
    long base = (long)mat * DM * DF;
    int c4 = (t & 15) * 4, r = t >> 4;
#pragma unroll
    for (int i = 0; i < 4; ++i) {
      float4 v = *(const float4*)&w1[base + (long)(R0 + r + 16 * i) * DF + C0 + c4];
      tile[r + 16 * i][c4 + 0] = v.x;
      tile[r + 16 * i][c4 + 1] = v.y;
      tile[r + 16 * i][c4 + 2] = v.z;
      tile[r + 16 * i][c4 + 3] = v.w;
    }
    __syncthreads();
#pragma unroll
    for (int p = 0; p < 2; ++p) {
      int u = t + p * 256;
      int c = u >> 3, r0 = (u & 7) * 8;
      u16x8 o;
#pragma unroll
      for (int k = 0; k < 8; ++k) o[k] = f2bf(tile[r0 + k][c]);
      *(u16x8*)&w1t[base + (long)(C0 + c) * DM + R0 + r0] = o;
    }
    return;
  }
  // ---- router (no atomics) ----
  int wave = t >> 6, lane = t & 63;
  int tok = b * 4 + wave;
  float ar[8], an[8];
#pragma unroll
  for (int e = 0; e < 8; ++e) { ar[e] = 0.f; an[e] = 0.f; }
#pragma unroll 4
  for (int k = 0; k < 16; ++k) {
    int d = lane + 64 * k;
    float xv = x[(long)tok * DM + d];
    xbf[(long)tok * DM + d] = f2bf(xv);
    float4 r0 = *(const float4*)&rw[d * 8];
    float4 r1 = *(const float4*)&rw[d * 8 + 4];
    float4 n0 = *(const float4*)&nw[d * 8];
    float4 n1 = *(const float4*)&nw[d * 8 + 4];
    ar[0] += xv * r0.x; ar[1] += xv * r0.y; ar[2] += xv * r0.z; ar[3] += xv * r0.w;
    ar[4] += xv * r1.x; ar[5] += xv * r1.y; ar[6] += xv * r1.z; ar[7] += xv * r1.w;
    an[0] += xv * n0.x; an[1] += xv * n0.y; an[2] += xv * n0.z; an[3] += xv * n0.w;
    an[4] += xv * n1.x; an[5] += xv * n1.y; an[6] += xv * n1.z; an[7] += xv * n1.w;
  }
#pragma unroll
  for (int off = 32; off; off >>= 1) {
#pragma unroll
    for (int e = 0; e < 8; ++e) {
      ar[e] += __shfl_xor(ar[e], off);
      an[e] += __shfl_xor(an[e], off);
    }
  }
  if (lane == 0) {
    float nz[8];
#pragma unroll
    for (int e = 0; e < 8; ++e) {
      float lg = ar[e] + rb[e];
      float z = an[e] + nb[e];
      float sp = fmaxf(z, 0.f) + log1pf(expf(-fabsf(z)));
      nz[e] = lg + noise[(long)tok * 8 + e] * sp;
    }
    int i0 = 0; float v0 = nz[0];
#pragma unroll
    for (int e = 1; e < 8; ++e) if (nz[e] > v0) { v0 = nz[e]; i0 = e; }
    int i1 = -1; float v1 = -3.4e38f;
#pragma unroll
    for (int e = 0; e < 8; ++e) if (e != i0 && nz[e] > v1) { v1 = nz[e]; i1 = e; }
    float g0 = 1.f / (1.f + expf(v1 - v0));
    float g1 = 1.f / (1.f + expf(v0 - v1));
#pragma unroll
    for (int e = 0; e < 8; ++e)
      out_gate[(long)tok * 8 + e] = (e == i0) ? g0 : ((e == i1) ? g1 : 0.f);
    tok_e[tok * 2] = i0; tok_e[tok * 2 + 1] = i1;
    tok_g[tok * 2] = g0; tok_g[tok * 2 + 1] = g1;
  }
}

// ---- build_lists: ONE block, 1024 threads, zero global atomics ----
__global__ __launch_bounds__(1024) void build_lists_kernel(
    const int* __restrict__ tok_e, const float* __restrict__ tok_g,
    int* __restrict__ counts_out, int* __restrict__ rowmap,
    float* __restrict__ rowgate) {
  __shared__ int scnt[NE];
  const int tid = threadIdx.x;
  const int lane = tid & 63;
  if (tid < NE) scnt[tid] = 0;
  __syncthreads();
#pragma unroll
  for (int it = 0; it < 8; ++it) {
    int idx = it * 1024 + tid;           // 0..8191
    int e = tok_e[idx];
#pragma unroll
    for (int ee = 0; ee < NE; ++ee) {
      unsigned long long m = __ballot(e == ee);
      if (m != 0ull && lane == __ffsll((unsigned long long)m) - 1)
        atomicAdd(&scnt[ee], (int)__popcll(m));
    }
  }
  __syncthreads();
  if (tid == 0) {
    int run = 0;
#pragma unroll
    for (int e = 0; e < NE; ++e) {
      int c = scnt[e];
      counts_out[e] = c;
      scnt[e] = run;
      run += c;
    }
  }
  __syncthreads();
#pragma unroll
  for (int it = 0; it < 8; ++it) {
    int idx = it * 1024 + tid;
    int e = tok_e[idx];
    float g = tok_g[idx];
    int tok = idx >> 1;
#pragma unroll
    for (int ee = 0; ee < NE; ++ee) {
      unsigned long long m = __ballot(e == ee);
      if (e == ee) {
        int leader = __ffsll((unsigned long long)m) - 1;
        int base = 0;
        if (lane == leader) base = atomicAdd(&scnt[ee], (int)__popcll(m));
        base = __shfl(base, leader);
        int rank = (int)__popcll(m & ((1ull << lane) - 1ull));
        int slot = base + rank;
        rowmap[slot] = tok;
        rowgate[slot] = g;
      }
    }
  }
}

// ---- 128x512xBK=32 GEMM core, 8 waves (2M x 4N, 64x128 each), 3x40KB, depth-2 ----
// Per 40KB buffer: A (128 rows x 64B) @0, B (512 rows x 64B) @8192.
// Row r, phys 16B chunk p holds source k-chunk p ^ (r&3).
// Stage: 5 gload16/thread (A:1, B:4); LDS dest linear tid*16 per 8KB region.
// Iter t: VM5 (tile t's 5 loads done; t+1's 5 in flight) -> barrier ->
// stage t+2 into freed buffer -> 4+8 ds_read_b128 -> lgkmcnt(0) -> 32 MFMA.
#define GEMM_PRE()                                                            \
  const int tid = threadIdx.x;                                                \
  const int w = tid >> 6, l = tid & 63;                                       \
  const int wr = w >> 2, wc = w & 3;                                          \
  const int fr = l & 15, fq = l >> 4;                                         \
  const int rS = tid >> 2;                                                    \
  const int sc = (tid & 3) ^ (rS & 3);                                        \
  const int dst = tid * 16;                                                   \
  const int rsz = (fq ^ (fr & 3)) * 16;                                       \
  const int aoff = (wr * 64 + fr) * 64 + rsz;                                 \
  const int boff = 8192 + (wc * 128 + fr) * 64 + rsz;

#define STAGE_TILE(WB, KT) do {                                               \
    gload16(pA0 + (long)(KT) * 64, (WB) + dst);                               \
    gload16(pB[0] + (long)(KT) * 64, (WB) + 8192 + dst);                      \
    gload16(pB[1] + (long)(KT) * 64, (WB) + 16384 + dst);                     \
    gload16(pB[2] + (long)(KT) * 64, (WB) + 24576 + dst);                     \
    gload16(pB[3] + (long)(KT) * 64, (WB) + 32768 + dst); } while (0)

#define READ_ALL(RB)                                                          \
  _Pragma("unroll") for (int mf = 0; mf < 4; ++mf)                            \
    A[mf] = *(const bf16x8*)((RB) + aoff + mf * 1024);                        \
  _Pragma("unroll") for (int nf = 0; nf < 8; ++nf)                            \
    B[nf] = *(const bf16x8*)((RB) + boff + nf * 1024);

#define MM_ALL do { __builtin_amdgcn_s_setprio(1);                            \
  _Pragma("unroll") for (int mf = 0; mf < 4; ++mf)                            \
  _Pragma("unroll") for (int nf = 0; nf < 8; ++nf)                            \
      acc[mf][nf] = MFMA16(A[mf], B[nf], acc[mf][nf]);                        \
  __builtin_amdgcn_s_setprio(0); } while (0)

#define KLOOP(NT) do {                                                        \
  char *q0 = buf0, *q1 = buf1, *q2 = buf2;                                    \
  STAGE_TILE(q0, 0); STAGE_TILE(q1, 1);                                       \
  for (int t = 0; t < (NT); ++t) {                                            \
    if (t + 1 < (NT)) { VM5; } else { VM0; }                                  \
    BARX;                                                                     \
    if (t + 2 < (NT)) STAGE_TILE(q2, t + 2);                                  \
    READ_ALL(q0);                                                             \
    LGKM0;                                                                    \
    MM_ALL;                                                                   \
    char* qt = q0; q0 = q1; q1 = q2; q2 = qt;                                 \
  } } while (0)

// --------- GEMM1 (persistent, XCD-chunked) + w2-transpose tail ---------
__global__ __launch_bounds__(512, 2) void gemm1_kernel(
    const unsigned short* __restrict__ xbf, const unsigned short* __restrict__ w1t,
    const float* __restrict__ b1, const int* __restrict__ rowmap,
    const int* __restrict__ counts, unsigned short* __restrict__ h,
    const float* __restrict__ w2, unsigned short* __restrict__ w2t) {
  __shared__ __align__(16) char Lds[122880];
  char* buf0 = Lds;
  char* buf1 = Lds + 40960;
  char* buf2 = Lds + 81920;

  GEMM_PRE();

  int cnts[NE], mbp[NE], base[NE], offe[NE];
  int Titems = 0, runoff = 0;
#pragma unroll
  for (int e = 0; e < NE; ++e) {
    cnts[e] = counts[e];
    offe[e] = runoff; runoff += cnts[e];
    mbp[e] = (cnts[e] + 127) >> 7;
    base[e] = Titems;
    Titems += mbp[e] * 8;               // nb = DF/512 = 8
  }
  const int xcd = blockIdx.x & 7, lane_in = blockIdx.x >> 3;
  const int chunk = (Titems + 7) >> 3;

  for (int j = lane_in; j < chunk; j += (PGRID >> 3)) {
    int wi = xcd * chunk + j;
    if (wi >= Titems) break;
    int eSel = 0;
#pragma unroll
    for (int ee = 1; ee < NE; ++ee) if (wi >= base[ee]) eSel = ee;
    int rem = wi - base[eSel];
    int mp = mbp[eSel];
    int nbi = rem / mp;                 // nb-major: neighbors share A/B panels in L2
    int mbi = rem - nbi * mp;
    int cnt = cnts[eSel];
    int m0 = mbi * 128, n0 = nbi * 512;
    int off = offe[eSel];

    int ra = m0 + rS; ra = (ra < cnt) ? ra : (cnt - 1);
    const char* pA0 = (const char*)xbf + (long)rowmap[off + ra] * (DM * 2) + sc * 16;
    const char* pB[4];
#pragma unroll
    for (int jj = 0; jj < 4; ++jj)
      pB[jj] = (const char*)w1t + ((long)eSel * DF * DM + (long)(n0 + jj * 128 + rS) * DM) * 2 + sc * 16;

    bf16x8 A[4], B[8];
    f32x4 acc[4][8];
#pragma unroll
    for (int i = 0; i < 4; ++i)
#pragma unroll
      for (int jj = 0; jj < 8; ++jj) acc[i][jj] = (f32x4){0.f, 0.f, 0.f, 0.f};

    KLOOP(DM / 32);

    float bias[8];
#pragma unroll
    for (int nf = 0; nf < 8; ++nf) bias[nf] = b1[eSel * DF + n0 + wc * 128 + nf * 16 + fr];
#pragma unroll
    for (int mf = 0; mf < 4; ++mf)
#pragma unroll
      for (int reg = 0; reg < 4; ++reg) {
        int rr = m0 + wr * 64 + mf * 16 + fq * 4 + reg;
        if (rr < cnt) {
          long hrow = (long)(off + rr) * DF;
#pragma unroll
          for (int nf = 0; nf < 8; ++nf) {
            int col = n0 + wc * 128 + nf * 16 + fr;
            h[hrow + col] = f2bf(fmaxf(acc[mf][nf][reg] + bias[nf], 0.f));
          }
        }
      }
    __syncthreads();   // protect LDS before next work item re-stages
  }

  // ---- tail: transpose w2 fp32 [e][4096][1024] -> bf16 w2t [e][1024][4096] ----
  float (*tf)[65] = (float(*)[65])Lds;
  for (int tt = blockIdx.x; tt < 8192; tt += PGRID) {
    __syncthreads();
    int mat = tt >> 10, ty = tt & 1023;
    int R0 = (ty >> 4) * 64, C0 = (ty & 15) * 64;   // R=4096, C=1024
    long wbase = (long)mat * DF * DM;
    int c4 = (tid & 15) * 4, r = tid >> 4;          // r: 0..31
#pragma unroll
    for (int i = 0; i < 2; ++i) {
      int row = r + 32 * i;
      float4 v = *(const float4*)&w2[wbase + (long)(R0 + row) * DM + C0 + c4];
      tf[row][c4 + 0] = v.x;
      tf[row][c4 + 1] = v.y;
      tf[row][c4 + 2] = v.z;
      tf[row][c4 + 3] = v.w;
    }
    __syncthreads();
    int c = tid >> 3, r0 = (tid & 7) * 8;
    u16x8 o;
#pragma unroll
    for (int k = 0; k < 8; ++k) o[k] = f2bf(tf[r0 + k][c]);
    *(u16x8*)&w2t[wbase + (long)(C0 + c) * DF + R0 + r0] = o;
  }
}

// ---------------- GEMM2 (persistent, XCD-chunked, split-K=4) ----------------
__global__ __launch_bounds__(512, 2) void gemm2_kernel(
    const unsigned short* __restrict__ hb, const unsigned short* __restrict__ w2t,
    const float* __restrict__ b2, const int* __restrict__ rowmap,
    const float* __restrict__ rowgate, const int* __restrict__ counts,
    float* __restrict__ out) {
  __shared__ __align__(16) char Lds[122880];
  char* buf0 = Lds;
  char* buf1 = Lds + 40960;
  char* buf2 = Lds + 81920;

  GEMM_PRE();

  int cnts[NE], mbp[NE], base[NE], offe[NE];
  int Titems = 0, runoff = 0;
#pragma unroll
  for (int e = 0; e < NE; ++e) {
    cnts[e] = counts[e];
    offe[e] = runoff; runoff += cnts[e];
    mbp[e] = (cnts[e] + 127) >> 7;
    base[e] = Titems;
    Titems += mbp[e] * 2 * SPLITK2;     // nb = DM/512 = 2, kc = 4
  }
  const int xcd = blockIdx.x & 7, lane_in = blockIdx.x >> 3;
  const int chunk = (Titems + 7) >> 3;

  for (int j = lane_in; j < chunk; j += (PGRID >> 3)) {
    int wi = xcd * chunk + j;
    if (wi >= Titems) break;
    int eSel = 0;
#pragma unroll
    for (int ee = 1; ee < NE; ++ee) if (wi >= base[ee]) eSel = ee;
    int rem = wi - base[eSel];
    int mp = mbp[eSel];
    int q = rem / mp;                   // q = kc*2 + nb, 0..7
    int mbi = rem - q * mp;
    int kc = q >> 1, nbi = q & 1;
    int cnt = cnts[eSel];
    int m0 = mbi * 128, n0 = nbi * 512;
    int off = offe[eSel];
    const long kcb = (long)kc * (DF / SPLITK2) * 2;

    int ra = m0 + rS; ra = (ra < cnt) ? ra : (cnt - 1);
    const char* pA0 = (const char*)hb + (long)(off + ra) * (DF * 2) + kcb + sc * 16;
    const char* pB[4];
#pragma unroll
    for (int jj = 0; jj < 4; ++jj)
      pB[jj] = (const char*)w2t + ((long)eSel * DM * DF + (long)(n0 + jj * 128 + rS) * DF) * 2 + kcb + sc * 16;

    bf16x8 A[4], B[8];
    f32x4 acc[4][8];
#pragma unroll
    for (int i = 0; i < 4; ++i)
#pragma unroll
      for (int jj = 0; jj < 8; ++jj) acc[i][jj] = (f32x4){0.f, 0.f, 0.f, 0.f};

    KLOOP(DF / SPLITK2 / 32);

    float bias[8];
#pragma unroll
    for (int nf = 0; nf < 8; ++nf)
      bias[nf] = (kc == 0) ? b2[eSel * DM + n0 + wc * 128 + nf * 16 + fr] : 0.f;
#pragma unroll
    for (int mf = 0; mf < 4; ++mf)
#pragma unroll
      for (int reg = 0; reg < 4; ++reg) {
        int rr = m0 + wr * 64 + mf * 16 + fq * 4 + reg;
        if (rr < cnt) {
          int slot = off + rr;
          int token = rowmap[slot];
          float g = rowgate[slot];
          float* orow = out + (long)token * DM;
#pragma unroll
          for (int nf = 0; nf < 8; ++nf) {
            int col = n0 + wc * 128 + nf * 16 + fr;
            atomicAdd(&orow[col], g * (acc[mf][nf][reg] + bias[nf]));
          }
        }
      }
    __syncthreads();   // protect LDS before next work item re-stages
  }
}

extern "C" void kernel_launch(void* const* d_in, const int* in_sizes, int n_in,
                              void* d_out, int out_size, void* d_ws, size_t ws_size,
                              hipStream_t stream) {
  const float* x     = (const float*)d_in[0];
  const float* noise = (const float*)d_in[1];
  const float* rw    = (const float*)d_in[2];
  const float* rb    = (const float*)d_in[3];
  const float* nw    = (const float*)d_in[4];
  const float* nb    = (const float*)d_in[5];
  const float* w1    = (const float*)d_in[6];
  const float* b1    = (const float*)d_in[7];
  const float* w2    = (const float*)d_in[8];
  const float* b2    = (const float*)d_in[9];
  float* out = (float*)d_out;
  float* out_gate = out + (long)T_TOK * DM;

  char* ws = (char*)d_ws;
  unsigned short* xbf = (unsigned short*)ws; ws += (size_t)T_TOK * DM * 2;
  unsigned short* w1t = (unsigned short*)ws; ws += (size_t)NE * DF * DM * 2;
  unsigned short* w2t = (unsigned short*)ws; ws += (size_t)NE * DM * DF * 2;
  unsigned short* hbuf = (unsigned short*)ws; ws += (size_t)(2 * T_TOK + 256) * DF * 2;
  int*   rowmap  = (int*)ws;   ws += (2 * T_TOK + 256) * 4;
  float* rowgate = (float*)ws; ws += (2 * T_TOK + 256) * 4;
  int*   tok_e   = (int*)ws;   ws += 2 * T_TOK * 4;
  float* tok_g   = (float*)ws; ws += 2 * T_TOK * 4;
  int*   counts  = (int*)ws;   ws += 64;

  hipMemsetAsync(d_out, 0, (size_t)out_size * 4, stream);

  prep_kernel<<<9216, 256, 0, stream>>>(w1, w1t, x, noise, rw, rb, nw, nb,
                                        out_gate, tok_e, tok_g, xbf);
  build_lists_kernel<<<1, 1024, 0, stream>>>(tok_e, tok_g, counts, rowmap, rowgate);
  gemm1_kernel<<<PGRID, 512, 0, stream>>>(xbf, w1t, b1, rowmap, counts, hbuf, w2, w2t);
  gemm2_kernel<<<PGRID, 512, 0, stream>>>(hbuf, w2t, b2, rowmap, rowgate, counts, out);
}

// Round 22
// 325.219 us; speedup vs baseline: 1.2481x; 1.2481x over previous
//
#include <hip/hip_runtime.h>
#include <hip/hip_bf16.h>
#include <stdint.h>

#define T_TOK 4096
#define DM 1024
#define DF 4096
#define NE 8
#define SPLITK2 2
#define PGRID 512

using bf16x8 = __attribute__((ext_vector_type(8))) short;
using f32x4  = __attribute__((ext_vector_type(4))) float;
using u16x8  = __attribute__((ext_vector_type(8))) unsigned short;

#define MFMA16(a, b, c) __builtin_amdgcn_mfma_f32_16x16x32_bf16((a), (b), (c), 0, 0, 0)
#define VM3 asm volatile("s_waitcnt vmcnt(3)" ::: "memory")
#define VM0 asm volatile("s_waitcnt vmcnt(0)" ::: "memory")
#define BARX do { __builtin_amdgcn_s_barrier(); __builtin_amdgcn_sched_barrier(0); } while (0)
#define LGKM0 do { asm volatile("s_waitcnt lgkmcnt(0)" ::: "memory"); \
                   __builtin_amdgcn_sched_barrier(0); } while (0)

__device__ __forceinline__ unsigned short f2bf(float f) {
  union { float f; uint32_t u; } v; v.f = f;
  return (unsigned short)((v.u + 0x7FFFu + ((v.u >> 16) & 1u)) >> 16);
}

__device__ __forceinline__ void gload16(const void* g, void* l) {
  __builtin_amdgcn_global_load_lds((const __attribute__((address_space(1))) void*)g,
                                   (__attribute__((address_space(3))) void*)l, 16, 0, 0);
}

// ------- fused prep: router (blocks 0..1023, no atomics) + w1 transpose (1024..9215) -------
__global__ __launch_bounds__(256) void prep_kernel(
    const float* __restrict__ w1, unsigned short* __restrict__ w1t,
    const float* __restrict__ x, const float* __restrict__ noise,
    const float* __restrict__ rw, const float* __restrict__ rb,
    const float* __restrict__ nw, const float* __restrict__ nb,
    float* __restrict__ out_gate,
    int* __restrict__ tok_e, float* __restrict__ tok_g,
    unsigned short* __restrict__ xbf) {
  __shared__ float tile[64][65];
  int b = blockIdx.x;
  int t = threadIdx.x;
  if (b >= 1024) {
    int bb = b - 1024;
    int mat = bb >> 10, ty = bb & 1023;
    int R0 = (ty >> 6) * 64, C0 = (ty & 63) * 64;   // R=1024, C=4096
    long base = (long)mat * DM * DF;
    int c4 = (t & 15) * 4, r = t >> 4;
#pragma unroll
    for (int i = 0; i < 4; ++i) {
      float4 v = *(const float4*)&w1[base + (long)(R0 + r + 16 * i) * DF + C0 + c4];
      tile[r + 16 * i][c4 + 0] = v.x;
      tile[r + 16 * i][c4 + 1] = v.y;
      tile[r + 16 * i][c4 + 2] = v.z;
      tile[r + 16 * i][c4 + 3] = v.w;
    }
    __syncthreads();
#pragma unroll
    for (int p = 0; p < 2; ++p) {
      int u = t + p * 256;
      int c = u >> 3, r0 = (u & 7) * 8;
      u16x8 o;
#pragma unroll
      for (int k = 0; k < 8; ++k) o[k] = f2bf(tile[r0 + k][c]);
      *(u16x8*)&w1t[base + (long)(C0 + c) * DM + R0 + r0] = o;
    }
    return;
  }
  // ---- router (no atomics) ----
  int wave = t >> 6, lane = t & 63;
  int tok = b * 4 + wave;
  float ar[8], an[8];
#pragma unroll
  for (int e = 0; e < 8; ++e) { ar[e] = 0.f; an[e] = 0.f; }
#pragma unroll 4
  for (int k = 0; k < 16; ++k) {
    int d = lane + 64 * k;
    float xv = x[(long)tok * DM + d];
    xbf[(long)tok * DM + d] = f2bf(xv);
    float4 r0 = *(const float4*)&rw[d * 8];
    float4 r1 = *(const float4*)&rw[d * 8 + 4];
    float4 n0 = *(const float4*)&nw[d * 8];
    float4 n1 = *(const float4*)&nw[d * 8 + 4];
    ar[0] += xv * r0.x; ar[1] += xv * r0.y; ar[2] += xv * r0.z; ar[3] += xv * r0.w;
    ar[4] += xv * r1.x; ar[5] += xv * r1.y; ar[6] += xv * r1.z; ar[7] += xv * r1.w;
    an[0] += xv * n0.x; an[1] += xv * n0.y; an[2] += xv * n0.z; an[3] += xv * n0.w;
    an[4] += xv * n1.x; an[5] += xv * n1.y; an[6] += xv * n1.z; an[7] += xv * n1.w;
  }
#pragma unroll
  for (int off = 32; off; off >>= 1) {
#pragma unroll
    for (int e = 0; e < 8; ++e) {
      ar[e] += __shfl_xor(ar[e], off);
      an[e] += __shfl_xor(an[e], off);
    }
  }
  if (lane == 0) {
    float nz[8];
#pragma unroll
    for (int e = 0; e < 8; ++e) {
      float lg = ar[e] + rb[e];
      float z = an[e] + nb[e];
      float sp = fmaxf(z, 0.f) + log1pf(expf(-fabsf(z)));
      nz[e] = lg + noise[(long)tok * 8 + e] * sp;
    }
    int i0 = 0; float v0 = nz[0];
#pragma unroll
    for (int e = 1; e < 8; ++e) if (nz[e] > v0) { v0 = nz[e]; i0 = e; }
    int i1 = -1; float v1 = -3.4e38f;
#pragma unroll
    for (int e = 0; e < 8; ++e) if (e != i0 && nz[e] > v1) { v1 = nz[e]; i1 = e; }
    float g0 = 1.f / (1.f + expf(v1 - v0));
    float g1 = 1.f / (1.f + expf(v0 - v1));
#pragma unroll
    for (int e = 0; e < 8; ++e)
      out_gate[(long)tok * 8 + e] = (e == i0) ? g0 : ((e == i1) ? g1 : 0.f);
    tok_e[tok * 2] = i0; tok_e[tok * 2 + 1] = i1;
    tok_g[tok * 2] = g0; tok_g[tok * 2 + 1] = g1;
  }
}

// ---- build_lists: ONE block, 1024 threads, zero global atomics ----
// pass1 ballot-histogram -> counts + prefix; pass2 ballot-rank slot assignment.
__global__ __launch_bounds__(1024) void build_lists_kernel(
    const int* __restrict__ tok_e, const float* __restrict__ tok_g,
    int* __restrict__ counts_out, int* __restrict__ rowmap,
    float* __restrict__ rowgate) {
  __shared__ int scnt[NE];
  const int tid = threadIdx.x;
  const int lane = tid & 63;
  if (tid < NE) scnt[tid] = 0;
  __syncthreads();
#pragma unroll
  for (int it = 0; it < 8; ++it) {
    int idx = it * 1024 + tid;           // 0..8191
    int e = tok_e[idx];
#pragma unroll
    for (int ee = 0; ee < NE; ++ee) {
      unsigned long long m = __ballot(e == ee);
      if (m != 0ull && lane == __ffsll((unsigned long long)m) - 1)
        atomicAdd(&scnt[ee], (int)__popcll(m));
    }
  }
  __syncthreads();
  if (tid == 0) {
    int run = 0;
#pragma unroll
    for (int e = 0; e < NE; ++e) {
      int c = scnt[e];
      counts_out[e] = c;
      scnt[e] = run;                     // cursor starts at expert offset
      run += c;
    }
  }
  __syncthreads();
#pragma unroll
  for (int it = 0; it < 8; ++it) {
    int idx = it * 1024 + tid;
    int e = tok_e[idx];
    float g = tok_g[idx];
    int tok = idx >> 1;
#pragma unroll
    for (int ee = 0; ee < NE; ++ee) {
      unsigned long long m = __ballot(e == ee);
      if (e == ee) {
        int leader = __ffsll((unsigned long long)m) - 1;
        int base = 0;
        if (lane == leader) base = atomicAdd(&scnt[ee], (int)__popcll(m));
        base = __shfl(base, leader);
        int rank = (int)__popcll(m & ((1ull << lane) - 1ull));
        int slot = base + rank;
        rowmap[slot] = tok;
        rowgate[slot] = g;
      }
    }
  }
}

// ---- 128x256xBK=32 GEMM core (best measured), 8 waves, 3x24KB buffers, depth-2 ----
#define GEMM_PRE()                                                            \
  const int tid = threadIdx.x;                                                \
  const int w = tid >> 6, l = tid & 63;                                       \
  const int wr = w >> 2, wc = w & 3;                                          \
  const int fr = l & 15, fq = l >> 4;                                         \
  const int rS = tid >> 2;                                                    \
  const int sc = (tid & 3) ^ (rS & 3);                                        \
  const int dst = tid * 16;                                                   \
  const int rsz = (fq ^ (fr & 3)) * 16;                                       \
  const int aoff = (wr * 64 + fr) * 64 + rsz;                                 \
  const int boff = 8192 + (wc * 64 + fr) * 64 + rsz;

#define STAGE_TILE(WB, KT) do {                                               \
    gload16(pA0 + (long)(KT) * 64, (WB) + dst);                               \
    gload16(pB[0] + (long)(KT) * 64, (WB) + 8192 + dst);                      \
    gload16(pB[1] + (long)(KT) * 64, (WB) + 16384 + dst); } while (0)

#define READ_ALL(RB)                                                          \
  _Pragma("unroll") for (int mf = 0; mf < 4; ++mf)                            \
    A[mf] = *(const bf16x8*)((RB) + aoff + mf * 1024);                        \
  _Pragma("unroll") for (int nf = 0; nf < 4; ++nf)                            \
    B[nf] = *(const bf16x8*)((RB) + boff + nf * 1024);

#define MM_ALL do { __builtin_amdgcn_s_setprio(1);                            \
  _Pragma("unroll") for (int mf = 0; mf < 4; ++mf)                            \
  _Pragma("unroll") for (int nf = 0; nf < 4; ++nf)                            \
      acc[mf][nf] = MFMA16(A[mf], B[nf], acc[mf][nf]);                        \
  __builtin_amdgcn_s_setprio(0); } while (0)

#define KLOOP(NT) do {                                                        \
  char *q0 = buf0, *q1 = buf1, *q2 = buf2;                                    \
  STAGE_TILE(q0, 0); STAGE_TILE(q1, 1);                                       \
  for (int t = 0; t < (NT); ++t) {                                            \
    if (t + 1 < (NT)) { VM3; } else { VM0; }                                  \
    BARX;                                                                     \
    if (t + 2 < (NT)) STAGE_TILE(q2, t + 2);                                  \
    READ_ALL(q0);                                                             \
    LGKM0;                                                                    \
    MM_ALL;                                                                   \
    char* qt = q0; q0 = q1; q1 = q2; q2 = qt;                                 \
  } } while (0)

// --------- GEMM1 (persistent, XCD-chunked) + w2-transpose tail ---------
__global__ __launch_bounds__(512, 4) void gemm1_kernel(
    const unsigned short* __restrict__ xbf, const unsigned short* __restrict__ w1t,
    const float* __restrict__ b1, const int* __restrict__ rowmap,
    const int* __restrict__ counts, unsigned short* __restrict__ h,
    const float* __restrict__ w2, unsigned short* __restrict__ w2t) {
  __shared__ __align__(16) char Lds[73728];
  char* buf0 = Lds;
  char* buf1 = Lds + 24576;
  char* buf2 = Lds + 49152;

  GEMM_PRE();

  int cnts[NE], mbp[NE], base[NE], offe[NE];
  int Titems = 0, runoff = 0;
#pragma unroll
  for (int e = 0; e < NE; ++e) {
    cnts[e] = counts[e];
    offe[e] = runoff; runoff += cnts[e];
    mbp[e] = (cnts[e] + 127) >> 7;
    base[e] = Titems;
    Titems += mbp[e] * 16;              // nb = DF/256 = 16
  }
  const int xcd = blockIdx.x & 7, lane_in = blockIdx.x >> 3;
  const int chunk = (Titems + 7) >> 3;

  for (int j = lane_in; j < chunk; j += (PGRID >> 3)) {
    int wi = xcd * chunk + j;
    if (wi >= Titems) break;
    int eSel = 0;
#pragma unroll
    for (int ee = 1; ee < NE; ++ee) if (wi >= base[ee]) eSel = ee;
    int rem = wi - base[eSel];
    int mp = mbp[eSel];
    int nbi = rem / mp;                 // nb-major: neighbors share B panel in L2
    int mbi = rem - nbi * mp;
    int cnt = cnts[eSel];
    int m0 = mbi * 128, n0 = nbi * 256;
    int off = offe[eSel];

    int ra = m0 + rS; ra = (ra < cnt) ? ra : (cnt - 1);
    const char* pA0 = (const char*)xbf + (long)rowmap[off + ra] * (DM * 2) + sc * 16;
    const char* pB[2];
#pragma unroll
    for (int jj = 0; jj < 2; ++jj)
      pB[jj] = (const char*)w1t + ((long)eSel * DF * DM + (long)(n0 + jj * 128 + rS) * DM) * 2 + sc * 16;

    bf16x8 A[4], B[4];
    f32x4 acc[4][4];
#pragma unroll
    for (int i = 0; i < 4; ++i)
#pragma unroll
      for (int jj = 0; jj < 4; ++jj) acc[i][jj] = (f32x4){0.f, 0.f, 0.f, 0.f};

    KLOOP(DM / 32);

    float bias[4];
#pragma unroll
    for (int nf = 0; nf < 4; ++nf) bias[nf] = b1[eSel * DF + n0 + wc * 64 + nf * 16 + fr];
#pragma unroll
    for (int mf = 0; mf < 4; ++mf)
#pragma unroll
      for (int reg = 0; reg < 4; ++reg) {
        int rr = m0 + wr * 64 + mf * 16 + fq * 4 + reg;
        if (rr < cnt) {
          long hrow = (long)(off + rr) * DF;
#pragma unroll
          for (int nf = 0; nf < 4; ++nf) {
            int col = n0 + wc * 64 + nf * 16 + fr;
            h[hrow + col] = f2bf(fmaxf(acc[mf][nf][reg] + bias[nf], 0.f));
          }
        }
      }
    __syncthreads();   // protect LDS before next work item re-stages
  }

  // ---- tail: transpose w2 fp32 [e][4096][1024] -> bf16 w2t [e][1024][4096] ----
  float (*tf)[65] = (float(*)[65])Lds;   // 64x65 floats, fits in 73728B
  for (int tt = blockIdx.x; tt < 8192; tt += PGRID) {
    __syncthreads();
    int mat = tt >> 10, ty = tt & 1023;
    int R0 = (ty >> 4) * 64, C0 = (ty & 15) * 64;   // R=4096, C=1024
    long wbase = (long)mat * DF * DM;
    int c4 = (tid & 15) * 4, r = tid >> 4;          // r: 0..31
#pragma unroll
    for (int i = 0; i < 2; ++i) {
      int row = r + 32 * i;
      float4 v = *(const float4*)&w2[wbase + (long)(R0 + row) * DM + C0 + c4];
      tf[row][c4 + 0] = v.x;
      tf[row][c4 + 1] = v.y;
      tf[row][c4 + 2] = v.z;
      tf[row][c4 + 3] = v.w;
    }
    __syncthreads();
    int c = tid >> 3, r0 = (tid & 7) * 8;
    u16x8 o;
#pragma unroll
    for (int k = 0; k < 8; ++k) o[k] = f2bf(tf[r0 + k][c]);
    *(u16x8*)&w2t[wbase + (long)(C0 + c) * DF + R0 + r0] = o;
  }
}

// ---------------- GEMM2 (persistent, XCD-chunked, split-K=2) ----------------
__global__ __launch_bounds__(512, 4) void gemm2_kernel(
    const unsigned short* __restrict__ hb, const unsigned short* __restrict__ w2t,
    const float* __restrict__ b2, const int* __restrict__ rowmap,
    const float* __restrict__ rowgate, const int* __restrict__ counts,
    float* __restrict__ out) {
  __shared__ __align__(16) char Lds[73728];
  char* buf0 = Lds;
  char* buf1 = Lds + 24576;
  char* buf2 = Lds + 49152;

  GEMM_PRE();

  int cnts[NE], mbp[NE], base[NE], offe[NE];
  int Titems = 0, runoff = 0;
#pragma unroll
  for (int e = 0; e < NE; ++e) {
    cnts[e] = counts[e];
    offe[e] = runoff; runoff += cnts[e];
    mbp[e] = (cnts[e] + 127) >> 7;
    base[e] = Titems;
    Titems += mbp[e] * 4 * SPLITK2;     // nb = DM/256 = 4, kc = 2
  }
  const int xcd = blockIdx.x & 7, lane_in = blockIdx.x >> 3;
  const int chunk = (Titems + 7) >> 3;

  for (int j = lane_in; j < chunk; j += (PGRID >> 3)) {
    int wi = xcd * chunk + j;
    if (wi >= Titems) break;
    int eSel = 0;
#pragma unroll
    for (int ee = 1; ee < NE; ++ee) if (wi >= base[ee]) eSel = ee;
    int rem = wi - base[eSel];
    int mp = mbp[eSel];
    int q = rem / mp;                   // q = kc*4 + nb
    int mbi = rem - q * mp;
    int kc = q >> 2, nbi = q & 3;
    int cnt = cnts[eSel];
    int m0 = mbi * 128, n0 = nbi * 256;
    int off = offe[eSel];
    const long kcb = (long)kc * (DF / SPLITK2) * 2;

    int ra = m0 + rS; ra = (ra < cnt) ? ra : (cnt - 1);
    const char* pA0 = (const char*)hb + (long)(off + ra) * (DF * 2) + kcb + sc * 16;
    const char* pB[2];
#pragma unroll
    for (int jj = 0; jj < 2; ++jj)
      pB[jj] = (const char*)w2t + ((long)eSel * DM * DF + (long)(n0 + jj * 128 + rS) * DF) * 2 + kcb + sc * 16;

    bf16x8 A[4], B[4];
    f32x4 acc[4][4];
#pragma unroll
    for (int i = 0; i < 4; ++i)
#pragma unroll
      for (int jj = 0; jj < 4; ++jj) acc[i][jj] = (f32x4){0.f, 0.f, 0.f, 0.f};

    KLOOP(DF / SPLITK2 / 32);

    float bias[4];
#pragma unroll
    for (int nf = 0; nf < 4; ++nf)
      bias[nf] = (kc == 0) ? b2[eSel * DM + n0 + wc * 64 + nf * 16 + fr] : 0.f;
#pragma unroll
    for (int mf = 0; mf < 4; ++mf)
#pragma unroll
      for (int reg = 0; reg < 4; ++reg) {
        int rr = m0 + wr * 64 + mf * 16 + fq * 4 + reg;
        if (rr < cnt) {
          int slot = off + rr;
          int token = rowmap[slot];
          float g = rowgate[slot];
          float* orow = out + (long)token * DM;
#pragma unroll
          for (int nf = 0; nf < 4; ++nf) {
            int col = n0 + wc * 64 + nf * 16 + fr;
            atomicAdd(&orow[col], g * (acc[mf][nf][reg] + bias[nf]));
          }
        }
      }
    __syncthreads();   // protect LDS before next work item re-stages
  }
}

extern "C" void kernel_launch(void* const* d_in, const int* in_sizes, int n_in,
                              void* d_out, int out_size, void* d_ws, size_t ws_size,
                              hipStream_t stream) {
  const float* x     = (const float*)d_in[0];
  const float* noise = (const float*)d_in[1];
  const float* rw    = (const float*)d_in[2];
  const float* rb    = (const float*)d_in[3];
  const float* nw    = (const float*)d_in[4];
  const float* nb    = (const float*)d_in[5];
  const float* w1    = (const float*)d_in[6];
  const float* b1    = (const float*)d_in[7];
  const float* w2    = (const float*)d_in[8];
  const float* b2    = (const float*)d_in[9];
  float* out = (float*)d_out;
  float* out_gate = out + (long)T_TOK * DM;

  char* ws = (char*)d_ws;
  unsigned short* xbf = (unsigned short*)ws; ws += (size_t)T_TOK * DM * 2;
  unsigned short* w1t = (unsigned short*)ws; ws += (size_t)NE * DF * DM * 2;
  unsigned short* w2t = (unsigned short*)ws; ws += (size_t)NE * DM * DF * 2;
  unsigned short* hbuf = (unsigned short*)ws; ws += (size_t)(2 * T_TOK + 256) * DF * 2;
  int*   rowmap  = (int*)ws;   ws += (2 * T_TOK + 256) * 4;
  float* rowgate = (float*)ws; ws += (2 * T_TOK + 256) * 4;
  int*   tok_e   = (int*)ws;   ws += 2 * T_TOK * 4;
  float* tok_g   = (float*)ws; ws += 2 * T_TOK * 4;
  int*   counts  = (int*)ws;   ws += 64;

  hipMemsetAsync(d_out, 0, (size_t)out_size * 4, stream);

  prep_kernel<<<9216, 256, 0, stream>>>(w1, w1t, x, noise, rw, rb, nw, nb,
                                        out_gate, tok_e, tok_g, xbf);
  build_lists_kernel<<<1, 1024, 0, stream>>>(tok_e, tok_g, counts, rowmap, rowgate);
  gemm1_kernel<<<PGRID, 512, 0, stream>>>(xbf, w1t, b1, rowmap, counts, hbuf, w2, w2t);
  gemm2_kernel<<<PGRID, 512, 0, stream>>>(hbuf, w2t, b2, rowmap, rowgate, counts, out);
}